// Round 4
// baseline (225.800 us; speedup 1.0000x reference)
//
#include <hip/hip_runtime.h>
#include <hip/hip_bf16.h>
#include <math.h>

#define B_ 4
#define N_ 4096
#define M_ 1024
#define C_ 384
#define NH_ 8
#define HD_ 48

typedef float f32x4 __attribute__((ext_vector_type(4)));
typedef short bf16x8 __attribute__((ext_vector_type(8)));

__device__ __forceinline__ unsigned short f2bf(float x) {  // RNE
    unsigned int u = __builtin_bit_cast(unsigned int, x);
    return (unsigned short)((u + 0x7FFFu + ((u >> 16) & 1u)) >> 16);
}
__device__ __forceinline__ unsigned short f2bf_trunc(float x) {
    return (unsigned short)(__builtin_bit_cast(unsigned int, x) >> 16);
}
__device__ __forceinline__ float bf2f(unsigned short x) {
    return __builtin_bit_cast(float, (unsigned int)x << 16);
}
__device__ __forceinline__ float fast_exp2(float x) {
#if __has_builtin(__builtin_amdgcn_exp2f)
    return __builtin_amdgcn_exp2f(x);
#else
    return exp2f(x);
#endif
}

// 48^-0.5 * log2(e): softmax via 2^x
#define QSCALE 0.20823490983597203f

// ---------------------------------------------------------------------------
// Transpose + convert weights: W[k][n] fp32 -> Wt[n][k] bf16. 64x64 tiles.
// ---------------------------------------------------------------------------
__global__ __launch_bounds__(256)
void transpose_w3(const float* __restrict__ Wq, const float* __restrict__ Wkv,
                  const float* __restrict__ Wproj,
                  unsigned short* __restrict__ Wq_t, unsigned short* __restrict__ Wkv_t,
                  unsigned short* __restrict__ Wproj_t)
{
    __shared__ unsigned short T[64 * 72];
    const int tid = threadIdx.x;
    int bid = blockIdx.x;
    const float* W; unsigned short* Wt; int N, kt, nt;
    if (bid < 36)       { W = Wq;    Wt = Wq_t;    N = 384; kt = bid / 6;  nt = bid - kt * 6; }
    else if (bid < 108) { bid -= 36;  W = Wkv;   Wt = Wkv_t;   N = 768; kt = bid / 12; nt = bid - kt * 12; }
    else                { bid -= 108; W = Wproj; Wt = Wproj_t; N = 384; kt = bid / 6;  nt = bid - kt * 6; }
    const int k0 = kt * 64, n0 = nt * 64;

    #pragma unroll
    for (int it = 0; it < 4; ++it) {
        int k = it * 16 + (tid >> 4);
        int n4 = (tid & 15) * 4;
        float4 v = *(const float4*)&W[(size_t)(k0 + k) * N + n0 + n4];
        T[(n4 + 0) * 72 + k] = f2bf(v.x);
        T[(n4 + 1) * 72 + k] = f2bf(v.y);
        T[(n4 + 2) * 72 + k] = f2bf(v.z);
        T[(n4 + 3) * 72 + k] = f2bf(v.w);
    }
    __syncthreads();
    #pragma unroll
    for (int i = 0; i < 2; ++i) {
        int s = tid + 256 * i;
        int n = s >> 3, part = s & 7;
        *(uint4*)&Wt[(size_t)(n0 + n) * C_ + k0 + part * 8] = *(const uint4*)&T[n * 72 + part * 8];
    }
}

// ---------------------------------------------------------------------------
// bf16 MFMA GEMM, 128x64 tile, A converted fp32->bf16 during staging.
// mode 0: bf1 = bf16 residual [B,N,384]; bf0 = bf16 Q*QSCALE [B,H,N,48]
// mode 1: bf0 = bf16 K [B,H,M,48]; bf1 = bf16 V^T [B,H,48,M]
// mode 2: out0(fp32) = acc + bf2f(addend) + bias   (A is bf16)
// ---------------------------------------------------------------------------
__global__ __launch_bounds__(256)
void gemm_bf16(const void* __restrict__ Av, const unsigned short* __restrict__ Wt,
               float* __restrict__ out0,
               unsigned short* __restrict__ bf0, unsigned short* __restrict__ bf1,
               const unsigned short* __restrict__ addend, const float* __restrict__ bias,
               int mode, int a_bf16)
{
    __shared__ unsigned short As[128 * 72];
    __shared__ unsigned short Ws[64 * 72];
    const int tid = threadIdx.x;
    const int wave = tid >> 6;
    const int lane = tid & 63;
    const int ln = lane & 15;
    const int quad = lane >> 4;
    const int row0 = blockIdx.x * 128;
    const int col0 = blockIdx.y * 64;

    f32x4 acc[2][4];
    #pragma unroll
    for (int rt = 0; rt < 2; ++rt)
        #pragma unroll
        for (int t = 0; t < 4; ++t) acc[rt][t] = (f32x4){0.f, 0.f, 0.f, 0.f};

    for (int kk = 0; kk < C_; kk += 64) {
        __syncthreads();
        if (a_bf16) {
            const unsigned short* A = (const unsigned short*)Av;
            #pragma unroll
            for (int i = 0; i < 4; ++i) {
                int s = tid + 256 * i;
                int r = s >> 3, part = s & 7;
                *(uint4*)&As[r * 72 + part * 8] =
                    *(const uint4*)&A[(size_t)(row0 + r) * C_ + kk + part * 8];
            }
        } else {
            const float* A = (const float*)Av;
            #pragma unroll
            for (int i = 0; i < 8; ++i) {
                int s = tid + 256 * i;
                int r = s >> 4, k4 = (s & 15) << 2;
                float4 v = *(const float4*)&A[(size_t)(row0 + r) * C_ + kk + k4];
                uint2 pk;
                pk.x = (unsigned int)f2bf(v.x) | ((unsigned int)f2bf(v.y) << 16);
                pk.y = (unsigned int)f2bf(v.z) | ((unsigned int)f2bf(v.w) << 16);
                *(uint2*)&As[r * 72 + k4] = pk;
            }
        }
        #pragma unroll
        for (int i = 0; i < 2; ++i) {
            int s = tid + 256 * i;
            int n = s >> 3, part = s & 7;
            *(uint4*)&Ws[n * 72 + part * 8] =
                *(const uint4*)&Wt[(size_t)(col0 + n) * C_ + kk + part * 8];
        }
        __syncthreads();

        bf16x8 af[2][2];
        #pragma unroll
        for (int rt = 0; rt < 2; ++rt) {
            const unsigned short* Ap = &As[(wave * 32 + rt * 16 + ln) * 72];
            af[rt][0] = *(const bf16x8*)&Ap[quad * 8];
            af[rt][1] = *(const bf16x8*)&Ap[32 + quad * 8];
        }
        #pragma unroll
        for (int t = 0; t < 4; ++t) {
            const unsigned short* Wp = &Ws[(t * 16 + ln) * 72];
            bf16x8 b0 = *(const bf16x8*)&Wp[quad * 8];
            bf16x8 b1 = *(const bf16x8*)&Wp[32 + quad * 8];
            #pragma unroll
            for (int rt = 0; rt < 2; ++rt) {
                acc[rt][t] = __builtin_amdgcn_mfma_f32_16x16x32_bf16(af[rt][0], b0, acc[rt][t], 0, 0, 0);
                acc[rt][t] = __builtin_amdgcn_mfma_f32_16x16x32_bf16(af[rt][1], b1, acc[rt][t], 0, 0, 0);
            }
        }
    }

    #pragma unroll
    for (int rt = 0; rt < 2; ++rt) {
        #pragma unroll
        for (int t = 0; t < 4; ++t) {
            int gcol = col0 + t * 16 + ln;
            #pragma unroll
            for (int r = 0; r < 4; ++r) {
                int grow = row0 + wave * 32 + rt * 16 + quad * 4 + r;
                float v = acc[rt][t][r];
                if (mode == 0) {
                    bf1[(size_t)grow * C_ + gcol] = f2bf(v);
                    int b = grow >> 12, n = grow & (N_ - 1);
                    int h = gcol / HD_, d = gcol - h * HD_;
                    bf0[(((size_t)(b * NH_ + h) * N_) + n) * HD_ + d] = f2bf(v * QSCALE);
                } else if (mode == 1) {
                    int b = grow >> 10, m = grow & (M_ - 1);
                    if (gcol < C_) {
                        int h = gcol / HD_, d = gcol - h * HD_;
                        bf0[(((size_t)(b * NH_ + h) * M_) + m) * HD_ + d] = f2bf(v);
                    } else {
                        int c2 = gcol - C_;
                        int h = c2 / HD_, d = c2 - h * HD_;
                        bf1[(((size_t)(b * NH_ + h) * HD_) + d) * M_ + m] = f2bf(v);
                    }
                } else {
                    size_t idx = (size_t)grow * C_ + gcol;
                    out0[idx] = v + bf2f(addend[idx]) + bias[gcol];
                }
            }
        }
    }
}

// ---------------------------------------------------------------------------
// Barrier-free MFMA attention. Block = 4 independent waves x 32 q-rows.
// K/V MFMA B-fragments loaded DIRECTLY from global (L1/L2-served); no LDS
// staging. HD=48 -> second K-chunk MFMA with quads 2,3 zeroed. Row sums via
// MFMA against constant all-ones B-frag. P round-trips per-wave LDS only.
// Grid (bh, qtile): blockid%8 pins h per XCD -> K/V L2-resident (768 KB/XCD).
// ---------------------------------------------------------------------------
__global__ __launch_bounds__(256, 4)
void attn_mfma(const unsigned short* __restrict__ qbf,
               const unsigned short* __restrict__ kbf,
               const unsigned short* __restrict__ vbf,
               unsigned short* __restrict__ of)
{
    __shared__ unsigned short P[4][2][16 * 72];

    const int tid = threadIdx.x;
    const int wave = tid >> 6;
    const int lane = tid & 63;
    const int ln = lane & 15;
    const int quad = lane >> 4;
    const int bh = blockIdx.x;
    const int n0 = blockIdx.y * 128 + wave * 32;

    const bf16x8 zero8 = (bf16x8){0, 0, 0, 0, 0, 0, 0, 0};
    bf16x8 ones8;
    #pragma unroll
    for (int i = 0; i < 8; ++i) ones8[i] = (short)0x3F80;

    // Q fragments (persist in registers). quads 2,3 of hi chunk read 16B past
    // the row (next row / next buffer) -- zeroed below, always in-bounds.
    bf16x8 q0[2], q1[2];
    const unsigned short* qsrc = qbf + ((size_t)bh * N_ + n0) * HD_;
    #pragma unroll
    for (int rt = 0; rt < 2; ++rt) {
        const unsigned short* qp = qsrc + (size_t)(rt * 16 + ln) * HD_;
        q0[rt] = *(const bf16x8*)(qp + quad * 8);
        q1[rt] = *(const bf16x8*)(qp + 32 + quad * 8);
        if (quad >= 2) q1[rt] = zero8;
    }

    f32x4 O[2][4];   // [row-tile][out-tile]; ot==3 accumulates row sums l
    #pragma unroll
    for (int rt = 0; rt < 2; ++rt)
        #pragma unroll
        for (int t = 0; t < 4; ++t) O[rt][t] = (f32x4){0.f, 0.f, 0.f, 0.f};

    const unsigned short* kb = kbf + (size_t)bh * M_ * HD_;
    const unsigned short* vb = vbf + (size_t)bh * HD_ * M_;
    unsigned short* Pw[2] = { &P[wave][0][0], &P[wave][1][0] };
    const int phys_r = (ln & 3) * 4 + (ln >> 2);

    for (int mt = 0; mt < M_ / 64; ++mt) {
        // ---- S = Q K^T (K frags direct from global) ----
        f32x4 S[2][4];
        #pragma unroll
        for (int rt = 0; rt < 2; ++rt)
            #pragma unroll
            for (int t = 0; t < 4; ++t) S[rt][t] = (f32x4){0.f, 0.f, 0.f, 0.f};
        const unsigned short* krow = kb + (size_t)mt * 64 * HD_;
        #pragma unroll
        for (int t = 0; t < 4; ++t) {
            const unsigned short* kp = krow + (size_t)(t * 16 + ln) * HD_;
            bf16x8 k0 = *(const bf16x8*)(kp + quad * 8);
            bf16x8 k1 = *(const bf16x8*)(kp + 32 + quad * 8);
            if (quad >= 2) k1 = zero8;
            #pragma unroll
            for (int rt = 0; rt < 2; ++rt) {
                S[rt][t] = __builtin_amdgcn_mfma_f32_16x16x32_bf16(q0[rt], k0, S[rt][t], 0, 0, 0);
                S[rt][t] = __builtin_amdgcn_mfma_f32_16x16x32_bf16(q1[rt], k1, S[rt][t], 0, 0, 0);
            }
        }

        // ---- P = exp2(S) -> per-wave LDS (permuted rows), read back A-frags ----
        bf16x8 p0[2], p1[2];
        #pragma unroll
        for (int rt = 0; rt < 2; ++rt) {
            #pragma unroll
            for (int t = 0; t < 4; ++t)
                #pragma unroll
                for (int r = 0; r < 4; ++r)
                    Pw[rt][(r * 4 + quad) * 72 + t * 16 + ln] =
                        f2bf_trunc(fast_exp2(S[rt][t][r]));
            const unsigned short* Pr = Pw[rt] + phys_r * 72;
            p0[rt] = *(const bf16x8*)(Pr + quad * 8);
            p1[rt] = *(const bf16x8*)(Pr + 32 + quad * 8);
        }

        // ---- O += P V (V frags direct from global), l += P @ ones ----
        #pragma unroll
        for (int ot = 0; ot < 3; ++ot) {
            const unsigned short* vp = vb + (size_t)(ot * 16 + ln) * M_ + mt * 64;
            bf16x8 v0 = *(const bf16x8*)(vp + quad * 8);
            bf16x8 v1 = *(const bf16x8*)(vp + 32 + quad * 8);
            #pragma unroll
            for (int rt = 0; rt < 2; ++rt) {
                O[rt][ot] = __builtin_amdgcn_mfma_f32_16x16x32_bf16(p0[rt], v0, O[rt][ot], 0, 0, 0);
                O[rt][ot] = __builtin_amdgcn_mfma_f32_16x16x32_bf16(p1[rt], v1, O[rt][ot], 0, 0, 0);
            }
        }
        #pragma unroll
        for (int rt = 0; rt < 2; ++rt) {
            O[rt][3] = __builtin_amdgcn_mfma_f32_16x16x32_bf16(p0[rt], ones8, O[rt][3], 0, 0, 0);
            O[rt][3] = __builtin_amdgcn_mfma_f32_16x16x32_bf16(p1[rt], ones8, O[rt][3], 0, 0, 0);
        }
    }

    // ---- epilogue: normalize by l (= O[rt][3], identical across cols) ----
    const int b = bh >> 3, h = bh & 7;
    #pragma unroll
    for (int rt = 0; rt < 2; ++rt) {
        float inv[4];
        #pragma unroll
        for (int r = 0; r < 4; ++r) inv[r] = 1.0f / O[rt][3][r];
        #pragma unroll
        for (int ot = 0; ot < 3; ++ot) {
            int gcol = h * HD_ + ot * 16 + ln;
            #pragma unroll
            for (int r = 0; r < 4; ++r) {
                int grow = n0 + rt * 16 + quad * 4 + r;
                of[((size_t)b * N_ + grow) * C_ + gcol] = f2bf(O[rt][ot][r] * inv[r]);
            }
        }
    }
}

extern "C" void kernel_launch(void* const* d_in, const int* in_sizes, int n_in,
                              void* d_out, int out_size, void* d_ws, size_t ws_size,
                              hipStream_t stream) {
    const float* q_x   = (const float*)d_in[0];
    const float* kv_x  = (const float*)d_in[1];
    const float* Wq    = (const float*)d_in[2];
    const float* Wkv   = (const float*)d_in[3];
    const float* Wproj = (const float*)d_in[4];
    const float* bproj = (const float*)d_in[5];
    float* out = (float*)d_out;

    unsigned short* qbf     = (unsigned short*)d_ws;  // [B,H,N,48] scaled
    unsigned short* kbf     = qbf     + 6291456;      // [B,H,M,48]   (qbf overreads spill here: ok)
    unsigned short* vbf     = kbf     + 1572864;      // [B,H,48,M]   (kbf overreads spill here: ok)
    unsigned short* qres    = vbf     + 1572864;      // [B,N,384] bf16 residual
    unsigned short* of      = qres    + 6291456;      // [B,N,384] bf16 attn out
    unsigned short* Wq_t    = of      + 6291456;      // [384][384]
    unsigned short* Wkv_t   = Wq_t    + 147456;       // [768][384]
    unsigned short* Wproj_t = Wkv_t   + 294912;       // [384][384]

    dim3 blk(256);

    transpose_w3<<<dim3(144), blk, 0, stream>>>(Wq, Wkv, Wproj, Wq_t, Wkv_t, Wproj_t);

    // q = q_x @ Wq -> qres (bf16 residual) + qbf (scaled, per-head)
    gemm_bf16<<<dim3(128, 6), blk, 0, stream>>>(
        q_x, Wq_t, nullptr, qbf, qres, nullptr, nullptr, 0, 0);

    // kv = kv_x @ Wkv -> kbf + vbf (V transposed)
    gemm_bf16<<<dim3(32, 12), blk, 0, stream>>>(
        kv_x, Wkv_t, nullptr, kbf, vbf, nullptr, nullptr, 1, 0);

    // attention (grid: bh fastest -> XCD pinned per h)
    attn_mfma<<<dim3(32, 32), blk, 0, stream>>>(qbf, kbf, vbf, of);

    // out = qres + of @ Wproj + bproj
    gemm_bf16<<<dim3(128, 6), blk, 0, stream>>>(
        of, Wproj_t, out, nullptr, nullptr, qres, bproj, 2, 1);
}

// Round 5
// 204.040 us; speedup vs baseline: 1.1066x; 1.1066x over previous
//
#include <hip/hip_runtime.h>
#include <hip/hip_bf16.h>
#include <math.h>

#define B_ 4
#define N_ 4096
#define M_ 1024
#define C_ 384
#define NH_ 8
#define HD_ 48

typedef float f32x4 __attribute__((ext_vector_type(4)));
typedef short bf16x8 __attribute__((ext_vector_type(8)));

__device__ __forceinline__ unsigned short f2bf(float x) {  // RNE
    unsigned int u = __builtin_bit_cast(unsigned int, x);
    return (unsigned short)((u + 0x7FFFu + ((u >> 16) & 1u)) >> 16);
}
__device__ __forceinline__ unsigned short f2bf_trunc(float x) {
    return (unsigned short)(__builtin_bit_cast(unsigned int, x) >> 16);
}
__device__ __forceinline__ float bf2f(unsigned short x) {
    return __builtin_bit_cast(float, (unsigned int)x << 16);
}
__device__ __forceinline__ float fast_exp2(float x) {
#if __has_builtin(__builtin_amdgcn_exp2f)
    return __builtin_amdgcn_exp2f(x);
#else
    return exp2f(x);
#endif
}
__device__ __forceinline__ uint2 pack4_rne(float a, float b, float c, float d) {
    uint2 r;
    r.x = (unsigned int)f2bf(a) | ((unsigned int)f2bf(b) << 16);
    r.y = (unsigned int)f2bf(c) | ((unsigned int)f2bf(d) << 16);
    return r;
}

// 48^-0.5 * log2(e): softmax via 2^x
#define QSCALE 0.20823490983597203f

// ---------------------------------------------------------------------------
// Convert activations fp32 -> bf16 (flat float4 grid; q_x then kv_x)
// ---------------------------------------------------------------------------
__global__ __launch_bounds__(256)
void conv_act(const float* __restrict__ a, unsigned short* __restrict__ da,
              const float* __restrict__ b, unsigned short* __restrict__ db)
{
    size_t i4 = (size_t)blockIdx.x * 256 + threadIdx.x;
    const float* src; unsigned short* dst;
    if (i4 < 1572864u) { src = a; dst = da; }
    else { src = b; dst = db; i4 -= 1572864u; }
    float4 v = *(const float4*)&src[i4 * 4];
    *(uint2*)&dst[i4 * 4] = pack4_rne(v.x, v.y, v.z, v.w);
}

// ---------------------------------------------------------------------------
// Transpose + convert weights: W[k][n] fp32 -> Wt[n][k] bf16. 64x64 tiles.
// ---------------------------------------------------------------------------
__global__ __launch_bounds__(256)
void transpose_w3(const float* __restrict__ Wq, const float* __restrict__ Wkv,
                  const float* __restrict__ Wproj,
                  unsigned short* __restrict__ Wq_t, unsigned short* __restrict__ Wkv_t,
                  unsigned short* __restrict__ Wproj_t)
{
    __shared__ unsigned short T[64 * 72];
    const int tid = threadIdx.x;
    int bid = blockIdx.x;
    const float* W; unsigned short* Wt; int N, kt, nt;
    if (bid < 36)       { W = Wq;    Wt = Wq_t;    N = 384; kt = bid / 6;  nt = bid - kt * 6; }
    else if (bid < 108) { bid -= 36;  W = Wkv;   Wt = Wkv_t;   N = 768; kt = bid / 12; nt = bid - kt * 12; }
    else                { bid -= 108; W = Wproj; Wt = Wproj_t; N = 384; kt = bid / 6;  nt = bid - kt * 6; }
    const int k0 = kt * 64, n0 = nt * 64;

    #pragma unroll
    for (int it = 0; it < 4; ++it) {
        int k = it * 16 + (tid >> 4);
        int n4 = (tid & 15) * 4;
        float4 v = *(const float4*)&W[(size_t)(k0 + k) * N + n0 + n4];
        T[(n4 + 0) * 72 + k] = f2bf(v.x);
        T[(n4 + 1) * 72 + k] = f2bf(v.y);
        T[(n4 + 2) * 72 + k] = f2bf(v.z);
        T[(n4 + 3) * 72 + k] = f2bf(v.w);
    }
    __syncthreads();
    #pragma unroll
    for (int i = 0; i < 2; ++i) {
        int s = tid + 256 * i;
        int n = s >> 3, part = s & 7;
        *(uint4*)&Wt[(size_t)(n0 + n) * C_ + k0 + part * 8] = *(const uint4*)&T[n * 72 + part * 8];
    }
}

// ---------------------------------------------------------------------------
// Hybrid GEMM: 128 rows x 64 cols per block. Whole W column-slice (64x384)
// staged to LDS ONCE (one barrier); A-fragments stream directly from global.
// Operand-swapped MFMA: D = mfma(Wfrag, Afrag) -> thread owns 4 consecutive
// output COLS at one row -> packed epilogue stores.
// mode 0: bf1 = bf16 residual [B,N,384]; bf0 = bf16 Q*QSCALE [B,H,N,48]
// mode 1: bf0 = bf16 K [B,H,M,48]; bf1 = bf16 V^T [B,H,48,M]
// mode 2: out0(fp32) = acc + bf2f(addend) + bias
// ---------------------------------------------------------------------------
__global__ __launch_bounds__(256)
void gemm_hyb(const unsigned short* __restrict__ A, const unsigned short* __restrict__ Wt,
              float* __restrict__ out0,
              unsigned short* __restrict__ bf0, unsigned short* __restrict__ bf1,
              const unsigned short* __restrict__ addend, const float* __restrict__ bias,
              int mode)
{
    __shared__ unsigned short Ws[64 * 392];   // [n][k], padded stride
    const int tid = threadIdx.x;
    const int wave = tid >> 6;
    const int lane = tid & 63;
    const int ln = lane & 15;
    const int quad = lane >> 4;
    const int row0 = blockIdx.x * 128;
    const int col0 = blockIdx.y * 64;

    // stage whole W slice once: 64 rows x 48 uint4
    for (int i = tid; i < 3072; i += 256) {
        int n = i / 48, part = i - n * 48;
        *(uint4*)&Ws[n * 392 + part * 8] = *(const uint4*)&Wt[(size_t)(col0 + n) * C_ + part * 8];
    }
    __syncthreads();

    f32x4 acc[2][4];
    #pragma unroll
    for (int rt = 0; rt < 2; ++rt)
        #pragma unroll
        for (int ct = 0; ct < 4; ++ct) acc[rt][ct] = (f32x4){0.f, 0.f, 0.f, 0.f};

    const unsigned short* arow0 = A + (size_t)(row0 + wave * 32 + ln) * C_;
    const unsigned short* arow1 = arow0 + 16 * C_;

    #pragma unroll
    for (int kc = 0; kc < 12; ++kc) {
        bf16x8 b0 = *(const bf16x8*)(arow0 + kc * 32 + quad * 8);
        bf16x8 b1 = *(const bf16x8*)(arow1 + kc * 32 + quad * 8);
        #pragma unroll
        for (int ct = 0; ct < 4; ++ct) {
            bf16x8 aw = *(const bf16x8*)&Ws[(ct * 16 + ln) * 392 + kc * 32 + quad * 8];
            acc[0][ct] = __builtin_amdgcn_mfma_f32_16x16x32_bf16(aw, b0, acc[0][ct], 0, 0, 0);
            acc[1][ct] = __builtin_amdgcn_mfma_f32_16x16x32_bf16(aw, b1, acc[1][ct], 0, 0, 0);
        }
    }

    // epilogue: row = row0+wave*32+rt*16+ln, cols = col0+ct*16+quad*4 .. +3
    #pragma unroll
    for (int rt = 0; rt < 2; ++rt) {
        int grow = row0 + wave * 32 + rt * 16 + ln;
        #pragma unroll
        for (int ct = 0; ct < 4; ++ct) {
            int gcb = col0 + ct * 16 + quad * 4;
            f32x4 v = acc[rt][ct];
            if (mode == 0) {
                *(uint2*)&bf1[(size_t)grow * C_ + gcb] = pack4_rne(v[0], v[1], v[2], v[3]);
                int b = grow >> 12, n = grow & (N_ - 1);
                int h = gcb / HD_, d = gcb - h * HD_;
                *(uint2*)&bf0[(((size_t)(b * NH_ + h) * N_) + n) * HD_ + d] =
                    pack4_rne(v[0] * QSCALE, v[1] * QSCALE, v[2] * QSCALE, v[3] * QSCALE);
            } else if (mode == 1) {
                int b = grow >> 10, m = grow & (M_ - 1);
                if (col0 < C_) {
                    int h = gcb / HD_, d = gcb - h * HD_;
                    *(uint2*)&bf0[(((size_t)(b * NH_ + h) * M_) + m) * HD_ + d] =
                        pack4_rne(v[0], v[1], v[2], v[3]);
                } else {
                    int c2 = gcb - C_;
                    int h = c2 / HD_, d = c2 - h * HD_;
                    size_t base = ((size_t)(b * NH_ + h) * HD_ + d) * M_ + m;
                    #pragma unroll
                    for (int r = 0; r < 4; ++r) bf1[base + (size_t)r * M_] = f2bf(v[r]);
                }
            } else {
                size_t idx = (size_t)grow * C_ + gcb;
                uint2 ad = *(const uint2*)&addend[idx];
                float4 bi = *(const float4*)&bias[gcb];
                float4 o;
                o.x = v[0] + bf2f((unsigned short)(ad.x & 0xFFFF)) + bi.x;
                o.y = v[1] + bf2f((unsigned short)(ad.x >> 16))    + bi.y;
                o.z = v[2] + bf2f((unsigned short)(ad.y & 0xFFFF)) + bi.z;
                o.w = v[3] + bf2f((unsigned short)(ad.y >> 16))    + bi.w;
                *(float4*)&out0[idx] = o;
            }
        }
    }
}

// ---------------------------------------------------------------------------
// MFMA attention, operand-swapped. Block = 4 waves x 32 q-rows; per-iter
// barrier keeps waves lockstep so K/V frag loads (direct from global) share
// L1. S' = mfma(K,Q) -> thread owns 4 consecutive m -> b64 P-writes.
// O' = mfma(V^T, P) -> thread owns 4 consecutive d, l per-lane (no shuffles
// until the end). Row sums accumulate in registers across all iters.
// ---------------------------------------------------------------------------
__global__ __launch_bounds__(256, 4)
void attn_mfma(const unsigned short* __restrict__ qbf,
               const unsigned short* __restrict__ kbf,
               const unsigned short* __restrict__ vbf,
               unsigned short* __restrict__ of)
{
    __shared__ unsigned short P[4][32 * 72];   // per-wave [q][m]

    const int tid = threadIdx.x;
    const int wave = tid >> 6;
    const int lane = tid & 63;
    const int ln = lane & 15;
    const int quad = lane >> 4;
    const int bh = blockIdx.x;
    const int n0w = blockIdx.y * 128 + wave * 32;

    const bf16x8 zero8 = (bf16x8){0, 0, 0, 0, 0, 0, 0, 0};

    // Q B-op fragments: lane ln = q-row; chunk1 quads>=2 are the d=48..64 pad.
    bf16x8 qb[2][2];
    #pragma unroll
    for (int qt = 0; qt < 2; ++qt) {
        const unsigned short* qp = qbf + ((size_t)bh * N_ + n0w + qt * 16 + ln) * HD_;
        qb[qt][0] = *(const bf16x8*)(qp + quad * 8);
        qb[qt][1] = *(const bf16x8*)(qp + 32 + quad * 8);   // overread ok (next rows)
        if (quad >= 2) qb[qt][1] = zero8;
    }

    f32x4 O[3][2];   // [d-tile][q-tile]
    #pragma unroll
    for (int ot = 0; ot < 3; ++ot)
        #pragma unroll
        for (int qt = 0; qt < 2; ++qt) O[ot][qt] = (f32x4){0.f, 0.f, 0.f, 0.f};
    float rs[2] = {0.f, 0.f};

    const unsigned short* kb = kbf + (size_t)bh * M_ * HD_;
    const unsigned short* vb = vbf + (size_t)bh * HD_ * M_;
    unsigned short* Pw = &P[wave][0];

    for (int mt = 0; mt < M_ / 64; ++mt) {
        __syncthreads();   // lockstep waves -> shared L1 lines for K/V

        // ---- S' = K Q^T : S'[m][q], m = t*16+quad*4+r, q = qt*16+ln ----
        f32x4 S[4][2];
        #pragma unroll
        for (int t = 0; t < 4; ++t)
            #pragma unroll
            for (int qt = 0; qt < 2; ++qt) S[t][qt] = (f32x4){0.f, 0.f, 0.f, 0.f};
        #pragma unroll
        for (int t = 0; t < 4; ++t) {
            const unsigned short* kp = kb + (size_t)(mt * 64 + t * 16 + ln) * HD_;
            bf16x8 k0 = *(const bf16x8*)(kp + quad * 8);
            bf16x8 k1 = *(const bf16x8*)(kp + 32 + quad * 8);
            if (quad >= 2) k1 = zero8;
            #pragma unroll
            for (int qt = 0; qt < 2; ++qt) {
                S[t][qt] = __builtin_amdgcn_mfma_f32_16x16x32_bf16(k0, qb[qt][0], S[t][qt], 0, 0, 0);
                S[t][qt] = __builtin_amdgcn_mfma_f32_16x16x32_bf16(k1, qb[qt][1], S[t][qt], 0, 0, 0);
            }
        }

        // ---- P = exp2(S'); b64 writes (4 consecutive m per thread) ----
        #pragma unroll
        for (int qt = 0; qt < 2; ++qt)
            #pragma unroll
            for (int t = 0; t < 4; ++t) {
                float p0 = fast_exp2(S[t][qt][0]);
                float p1 = fast_exp2(S[t][qt][1]);
                float p2 = fast_exp2(S[t][qt][2]);
                float p3 = fast_exp2(S[t][qt][3]);
                rs[qt] += (p0 + p1) + (p2 + p3);
                uint2 pk;
                pk.x = (unsigned int)f2bf_trunc(p0) | ((unsigned int)f2bf_trunc(p1) << 16);
                pk.y = (unsigned int)f2bf_trunc(p2) | ((unsigned int)f2bf_trunc(p3) << 16);
                *(uint2*)&Pw[(qt * 16 + ln) * 72 + t * 16 + quad * 4] = pk;
            }

        // ---- V loads (independent of P round-trip; fills the lgkm window) --
        bf16x8 va[3][2];
        #pragma unroll
        for (int ot = 0; ot < 3; ++ot) {
            const unsigned short* vp = vb + (size_t)(ot * 16 + ln) * M_ + mt * 64;
            va[ot][0] = *(const bf16x8*)(vp + quad * 8);
            va[ot][1] = *(const bf16x8*)(vp + 32 + quad * 8);
        }

        // ---- P B-op frags; O' += V^T P^T ----
        bf16x8 pb[2][2];
        #pragma unroll
        for (int qt = 0; qt < 2; ++qt) {
            const unsigned short* Pr = &Pw[(qt * 16 + ln) * 72];
            pb[qt][0] = *(const bf16x8*)(Pr + quad * 8);
            pb[qt][1] = *(const bf16x8*)(Pr + 32 + quad * 8);
        }
        #pragma unroll
        for (int ot = 0; ot < 3; ++ot)
            #pragma unroll
            for (int qt = 0; qt < 2; ++qt) {
                O[ot][qt] = __builtin_amdgcn_mfma_f32_16x16x32_bf16(va[ot][0], pb[qt][0], O[ot][qt], 0, 0, 0);
                O[ot][qt] = __builtin_amdgcn_mfma_f32_16x16x32_bf16(va[ot][1], pb[qt][1], O[ot][qt], 0, 0, 0);
            }
    }

    // ---- l[q] = sum over quads of rs; per-lane, 2 shuffles ----
    float inv[2];
    #pragma unroll
    for (int qt = 0; qt < 2; ++qt) {
        float x = rs[qt];
        x += __shfl_xor(x, 16);
        x += __shfl_xor(x, 32);
        inv[qt] = 1.0f / x;
    }

    // ---- epilogue: thread owns 4 consecutive d at q = qt*16+ln ----
    const int b = bh >> 3, h = bh & 7;
    #pragma unroll
    for (int ot = 0; ot < 3; ++ot)
        #pragma unroll
        for (int qt = 0; qt < 2; ++qt) {
            size_t grow = (size_t)b * N_ + n0w + qt * 16 + ln;
            int gcol = h * HD_ + ot * 16 + quad * 4;
            *(uint2*)&of[grow * C_ + gcol] =
                pack4_rne(O[ot][qt][0] * inv[qt], O[ot][qt][1] * inv[qt],
                          O[ot][qt][2] * inv[qt], O[ot][qt][3] * inv[qt]);
        }
}

extern "C" void kernel_launch(void* const* d_in, const int* in_sizes, int n_in,
                              void* d_out, int out_size, void* d_ws, size_t ws_size,
                              hipStream_t stream) {
    const float* q_x   = (const float*)d_in[0];
    const float* kv_x  = (const float*)d_in[1];
    const float* Wq    = (const float*)d_in[2];
    const float* Wkv   = (const float*)d_in[3];
    const float* Wproj = (const float*)d_in[4];
    const float* bproj = (const float*)d_in[5];
    float* out = (float*)d_out;

    unsigned short* qx_bf   = (unsigned short*)d_ws;  // [B,N,384] (reused as `of`)
    unsigned short* kvx_bf  = qx_bf  + 6291456;       // [B,M,384]
    unsigned short* qbf     = kvx_bf + 1572864;       // [B,H,N,48] scaled
    unsigned short* kbf     = qbf    + 6291456;       // [B,H,M,48]
    unsigned short* vbf     = kbf    + 1572864;       // [B,H,48,M]
    unsigned short* qres    = vbf    + 1572864;       // [B,N,384] bf16 residual
    unsigned short* Wq_t    = qres   + 6291456;       // [384][384]
    unsigned short* Wkv_t   = Wq_t   + 147456;        // [768][384]
    unsigned short* Wproj_t = Wkv_t  + 294912;        // [384][384]
    unsigned short* of      = qx_bf;                  // alias: dead after q-proj

    dim3 blk(256);

    conv_act<<<dim3(7680), blk, 0, stream>>>(q_x, qx_bf, kv_x, kvx_bf);
    transpose_w3<<<dim3(144), blk, 0, stream>>>(Wq, Wkv, Wproj, Wq_t, Wkv_t, Wproj_t);

    // q = q_x @ Wq -> qres (bf16 residual) + qbf (scaled, per-head)
    gemm_hyb<<<dim3(128, 6), blk, 0, stream>>>(
        qx_bf, Wq_t, nullptr, qbf, qres, nullptr, nullptr, 0);

    // kv = kv_x @ Wkv -> kbf + vbf (V transposed)
    gemm_hyb<<<dim3(32, 12), blk, 0, stream>>>(
        kvx_bf, Wkv_t, nullptr, kbf, vbf, nullptr, nullptr, 1);

    // attention
    attn_mfma<<<dim3(32, 32), blk, 0, stream>>>(qbf, kbf, vbf, of);

    // out = qres + of @ Wproj + bproj
    gemm_hyb<<<dim3(128, 6), blk, 0, stream>>>(
        of, Wproj_t, out, nullptr, nullptr, qres, bproj, 2);
}